// Round 4
// baseline (640.025 us; speedup 1.0000x reference)
//
#include <hip/hip_runtime.h>

typedef _Float16 f16x8 __attribute__((ext_vector_type(8)));
typedef float    f32x4 __attribute__((ext_vector_type(4)));

constexpr int Nn = 32, Cc = 256, HW = 1024, Mm = 2000, Tt = 32768;
constexpr int TB = 64;        // tokens per block (4 token-groups x 16)
constexpr int XROW = 264;     // X row stride (f16): 528 B rows, 16B-aligned rows
constexpr int YROW = 257;     // y accum row stride (fp32)
constexpr int LCAP = 768;     // candidate cap (expected ~436/block, +16 sigma; sized so LDS<=78KB -> 2 blocks/CU)
constexpr int NT = 63;        // M tiles of 32 rows (62 full + 16-row tail)
constexpr float LAMBDA = 0.0025f;
constexpr float PLO = LAMBDA * (1.0f - 3e-3f);   // borderline window (covers GEMM noise + Z regroup)
constexpr float PHI = LAMBDA * (1.0f + 3e-3f);
constexpr float ECUT = 4.8f;  // candidate cut (unchanged per-logit arithmetic -> same set)
constexpr float SCL = 4096.0f, ISCL = 1.0f / 4096.0f;

__global__ void wcvt_kernel(const float* __restrict__ w,
                            _Float16* __restrict__ whi, _Float16* __restrict__ wlo) {
  int i = blockIdx.x * 256 + threadIdx.x;
  if (i < Mm * Cc) {
    float v = w[i];
    _Float16 h = (_Float16)v;
    whi[i] = h;
    wlo[i] = (_Float16)((v - (float)h) * SCL);
  }
}

__device__ __forceinline__ void gl_lds16(const void* g, void* l) {
  __builtin_amdgcn_global_load_lds(
      (const __attribute__((address_space(1))) void*)g,
      (__attribute__((address_space(3))) void*)l, 16, 0, 0);
}

// R2 -> R3/R4: LDS 93.7KB limited us to 1 block/CU (Occupancy 22%), so every per-tile
// barrier's vmcnt(0) drain was fully exposed. LCAP 2048->768 brings LDS to 78.1KB
// -> 2 blocks/CU; co-resident blocks hide each other's drains (m114 overlap).
// launch_bounds(512,4): 4 waves/SIMD needs <=128 VGPR (we use ~100 incl AGPR).
// (R3 bench was an infra flake -- container failed twice, no dispatch ran; this is
// the same kernel resubmitted so the experiment actually gets measured.)
__global__ __launch_bounds__(512, 4)
void fused_mem_kernel(const float* __restrict__ x, const float* __restrict__ wgt,
                      const _Float16* __restrict__ whi, const _Float16* __restrict__ wlo,
                      float* __restrict__ y_out, float* __restrict__ att_out) {
  // region: X stage f16[64][264] x2 = 67584 B -> B dbuf 2x32768 B -> yL f32[64][257]
  __shared__ __align__(16) float bufB[TB * XROW];   // 67584 B
  __shared__ int   lm[LCAP];
  __shared__ float le[LCAP];
  __shared__ float la[LCAP];
  __shared__ float Zred[128];
  __shared__ float invZ[TB];
  __shared__ float l1s[TB];
  __shared__ float dens[TB];
  __shared__ int   lcnt;
  _Float16* Xh = (_Float16*)bufB;
  _Float16* Xl = Xh + TB * XROW;
  float*    yL = bufB;
  char*     Bb = (char*)bufB;

  const int tid = threadIdx.x;
  const int wv  = tid >> 6;                 // 0..7
  const int l   = tid & 63;
  const int qw  = l >> 4;
  const int lr  = l & 15;
  const int tg  = wv & 3;                   // token group (16 tokens)
  const int mh  = wv >> 2;                  // M half within 32-row tile
  const int t0  = blockIdx.x * TB;
  const int n   = t0 >> 10;
  const int hw0 = t0 & 1023;

  if (tid == 0) lcnt = 0;
  if (tid < TB) l1s[tid] = 0.f;

  // ---- phase 1: X tile (64 tokens x 256 c) -> LDS f16 hi/lo ----
  {
    const int h = tid & 63, cb = tid >> 6;
    const float* xp = x + ((size_t)n * Cc) * HW + hw0 + h;
    #pragma unroll
    for (int j = 0; j < 32; ++j) {
      int c = cb * 32 + j;
      float v = xp[(size_t)c * HW];          // 64 lanes consecutive: 256B chunks
      _Float16 hh = (_Float16)v;
      Xh[h * XROW + c] = hh;
      Xl[h * XROW + c] = (_Float16)((v - (float)hh) * SCL);
    }
  }
  __syncthreads();                                  // B1

  // A fragments (this wave's 16 tokens) -> regs; per-logit layout identical to R1/R2
  f16x8 ahi[8], alo[8];
  #pragma unroll
  for (int ks = 0; ks < 8; ++ks) {
    ahi[ks] = *(const f16x8*)&Xh[(tg * 16 + lr) * XROW + ks * 32 + qw * 8];
    alo[ks] = *(const f16x8*)&Xl[(tg * 16 + lr) * XROW + ks * 32 + qw * 8];
  }
  __syncthreads();                                  // B1b: X region now free -> B dbuf

  // B staging: linear LDS dest, PRE-SWIZZLED global source (chunk ^= row&7) so the
  // swizzled ds_read below is conflict-minimal (512B rows alias banks otherwise).
  auto stage = [&](int b, int tile) {
    char* base = Bb + b * 32768;
    #pragma unroll
    for (int i = 0; i < 4; ++i) {
      const int bu = i * 512 + wv * 64;             // wave-uniform 16B-chunk base
      const int u2 = (bu + l) & 1023;
      const int row = u2 >> 5, chunk = u2 & 31;
      int mrow = tile * 32 + row; mrow = mrow < Mm ? mrow : (Mm - 1);  // tail clamp (unused rows)
      const char* src = (const char*)(i < 2 ? whi : wlo)
                      + (size_t)mrow * 512 + ((chunk ^ (row & 7)) << 4);
      gl_lds16(src, base + bu * 16);
    }
  };

  stage(0, 0);
  __syncthreads();                                  // B1c: tile0 landed (vmcnt drained)

  float zp[4] = {0.f, 0.f, 0.f, 0.f};
  const int rrow = mh * 16 + lr;                    // W row within 32-row tile
  const int rsw  = rrow & 7;
  int cur = 0;
  for (int t = 0; t < NT; ++t) {
    if (t + 1 < NT) stage(cur ^ 1, t + 1);          // prefetch flies under compute

    // att background zeroing (block-exclusive slice; replaces the ~260us hipMemset)
    {
      int m = t * 32 + (tid >> 4);
      if (m < Mm) {
        f32x4 z4 = {0.f, 0.f, 0.f, 0.f};
        *(f32x4*)(att_out + ((size_t)(n * Mm + m)) * HW + hw0 + ((tid & 15) << 2)) = z4;
      }
    }

    if (mh == 0 || t < NT - 1) {                    // tail tile has 16 valid rows
      const char* bb = Bb + cur * 32768;
      f16x8 bh[8], bl[8];
      #pragma unroll
      for (int ks = 0; ks < 8; ++ks) {
        const int ch = (((ks * 4 + qw) ^ rsw) << 4);
        bh[ks] = *(const f16x8*)(bb + rrow * 512 + ch);
        bl[ks] = *(const f16x8*)(bb + 16384 + rrow * 512 + ch);
      }
      f32x4 ahh = {0.f, 0.f, 0.f, 0.f};
      f32x4 axl = {0.f, 0.f, 0.f, 0.f};
      f32x4 alh = {0.f, 0.f, 0.f, 0.f};             // 3 independent 8-chains (ILP)
      #pragma unroll
      for (int ks = 0; ks < 8; ++ks) {
        ahh = __builtin_amdgcn_mfma_f32_16x16x32_f16(ahi[ks], bh[ks], ahh, 0, 0, 0);
        axl = __builtin_amdgcn_mfma_f32_16x16x32_f16(ahi[ks], bl[ks], axl, 0, 0, 0);
        alh = __builtin_amdgcn_mfma_f32_16x16x32_f16(alo[ks], bh[ks], alh, 0, 0, 0);
      }
      const int mrow_ = t * 32 + rrow;
      #pragma unroll
      for (int r = 0; r < 4; ++r) {
        float s = fmaf(axl[r] + alh[r], ISCL, ahh[r]);   // logit, bit-identical to R2
        float e = __expf(s);
        zp[r] += e;
        if (e > ECUT) {                                  // ~0.3% taken
          int slot = atomicAdd(&lcnt, 1);
          if (slot < LCAP) { lm[slot] = ((tg * 16 + qw * 4 + r) << 16) | mrow_; le[slot] = e; }
        }
      }
    }
    __syncthreads();                                // per-tile: 1 barrier, vmcnt drained here
    cur ^= 1;
  }

  #pragma unroll
  for (int o = 1; o < 16; o <<= 1)
    #pragma unroll
    for (int r = 0; r < 4; ++r) zp[r] += __shfl_xor(zp[r], o);
  if (lr == 0) {
    #pragma unroll
    for (int r = 0; r < 4; ++r) Zred[mh * 64 + tg * 16 + qw * 4 + r] = zp[r];
  }
  __syncthreads();                                  // B2

  if (tid < TB) invZ[tid] = 1.f / (Zred[tid] + Zred[64 + tid]);
  __syncthreads();                                  // B3

  // ---- phase 4: candidate scan (exact fp32 recompute of borderline) + L1 ----
  const int ne = min(lcnt, LCAP);
  for (int e = tid; e < ne; e += 512) {
    const int tm = lm[e];
    const int t = tm >> 16, m = tm & 0xFFFF;
    float p = le[e] * invZ[t];
    float a = 0.f;
    if (p > PLO) {
      float pu = p;
      if (p < PHI) {
        // borderline (~few per block): exact fp32 dot from global x, W
        const float* xr = x + ((size_t)n * Cc) * HW + hw0 + t;
        const float* wr = wgt + (size_t)m * Cc;
        float s = 0.f;
        for (int c = 0; c < Cc; ++c) s = fmaf(xr[(size_t)c * HW], wr[c], s);
        pu = expf(s) * invZ[t];
      }
      float d = pu - LAMBDA;
      if (d > 0.f) {
        a = (d * pu) / (d + 1e-12f);
        atomicAdd(&l1s[t], a);
      }
    }
    la[e] = a;
  }
  __syncthreads();                                  // B4

  if (tid < TB) dens[tid] = fmaxf(l1s[tid], 1e-12f);
  for (int i = tid; i < TB * YROW; i += 512) yL[i] = 0.f;   // B dbuf dead; alias reuse
  __syncthreads();                                  // B5

  // ---- phase 6: sparse GEMM2 from survivor list (fp32 W) + att scatter ----
  // y accum layout PERMUTED: channel c lives at t*YROW + ((c&3)<<6 | c>>2).
  // phase-6 atomics then have lane-stride 4B (2 lanes/bank = free) instead of the
  // 16B-stride 8-way conflict that dominated R2's 16.6M SQ_LDS_BANK_CONFLICT.
  for (int e = wv; e < ne; e += 8) {                // wave-uniform entry -> no divergence
    float av = la[e];
    if (av > 0.f) {
      const int tm = lm[e];
      const int t = tm >> 16, m = tm & 0xFFFF;
      const float a = av / dens[t];
      float4 wf = *(const float4*)(wgt + (size_t)m * Cc + l * 4);   // c = 4l+i
      float* yr = yL + t * YROW + l;                // acc idx of c=4l+i is (i<<6)+l
      atomicAdd(yr + 0,   a * wf.x);
      atomicAdd(yr + 64,  a * wf.y);
      atomicAdd(yr + 128, a * wf.z);
      atomicAdd(yr + 192, a * wf.w);
      if (l == 0)
        att_out[((size_t)(n * Mm + m)) * HW + hw0 + t] = a;   // bg zeroed in-loop above
    }
  }
  __syncthreads();                                  // B6

  // ---- phase 7: y write (256B chunks: 64 consecutive hw per c); un-permute accum ----
  {
    const int h = tid & 63, cb = tid >> 6;
    float* yp = y_out + ((size_t)n * Cc) * HW + hw0 + h;
    #pragma unroll
    for (int j = 0; j < 32; ++j) {
      int c = cb * 32 + j;
      yp[(size_t)c * HW] = yL[h * YROW + (((c & 3) << 6) | (c >> 2))];
    }
  }
}

extern "C" void kernel_launch(void* const* d_in, const int* in_sizes, int n_in,
                              void* d_out, int out_size, void* d_ws, size_t ws_size,
                              hipStream_t stream) {
  const float* x = (const float*)d_in[0];
  const float* w = (const float*)d_in[1];
  float* y_out   = (float*)d_out;
  float* att_out = y_out + (size_t)Nn * Cc * HW;
  _Float16* whi = (_Float16*)d_ws;                  // 1.024 MB
  _Float16* wlo = whi + (size_t)Mm * Cc;            // 1.024 MB

  // no hipMemsetAsync: att background is zeroed in-kernel (block-exclusive slices);
  // the memset also evicted W from L2 before GEMM1.
  wcvt_kernel<<<(Mm * Cc + 255) / 256, 256, 0, stream>>>(w, whi, wlo);
  fused_mem_kernel<<<Tt / TB, 512, 0, stream>>>(x, w, whi, wlo, y_out, att_out);
}

// Round 5
// 588.384 us; speedup vs baseline: 1.0878x; 1.0878x over previous
//
#include <hip/hip_runtime.h>

typedef _Float16 f16x8 __attribute__((ext_vector_type(8)));
typedef float    f32x4 __attribute__((ext_vector_type(4)));

constexpr int Nn = 32, Cc = 256, HW = 1024, Mm = 2000, Tt = 32768;
constexpr int TB = 64;        // tokens per block (2 token-pairs x 32)
constexpr int XROW = 264;     // X row stride (f16): 528 B rows, 16B-aligned rows
constexpr int YROW = 257;     // y accum row stride (fp32)
constexpr int LCAP = 768;     // candidate cap (expected ~436/block; validated in R4)
constexpr int NT = 32;        // M tiles of 64 rows (31 full + 16-row tail)
constexpr float LAMBDA = 0.0025f;
constexpr float PLO = LAMBDA * (1.0f - 3e-3f);   // borderline window (covers GEMM noise + Z regroup)
constexpr float PHI = LAMBDA * (1.0f + 3e-3f);
constexpr float ECUT = 4.8f;  // candidate cut (per-logit e bits unchanged -> same set)
constexpr float SCL = 4096.0f, ISCL = 1.0f / 4096.0f;

__global__ void wcvt_kernel(const float* __restrict__ w,
                            _Float16* __restrict__ whi, _Float16* __restrict__ wlo) {
  int i = blockIdx.x * 256 + threadIdx.x;
  if (i < Mm * Cc) {
    float v = w[i];
    _Float16 h = (_Float16)v;
    whi[i] = h;
    wlo[i] = (_Float16)((v - (float)h) * SCL);
  }
}

__device__ __forceinline__ void gl_lds16(const void* g, void* l) {
  __builtin_amdgcn_global_load_lds(
      (const __attribute__((address_space(1))) void*)g,
      (__attribute__((address_space(3))) void*)l, 16, 0, 0);
}

// R4 post-mortem: LDS READ pipe is the bottleneck (16.5M ds_read_b128 ~= 240us of
// the 326us R2 time; conflicts counter == read count across rounds). Old layout
// read each B byte 4x (4 token-group waves). New layout: waves = 2 token-pairs x
// 4 M-quarters; each wave owns 32 tokens (2 A-frag sets) x 16 W rows; tile = 64
// rows. B redundancy 4x -> 2x: LDS traffic/CU ~269us-equiv -> ~165us-equiv.
// launch_bounds(512,2): 256-reg budget for the ~215-reg working set (R4's (512,4)
// forced 128 regs -> scratch spills -> +100MB FETCH/WRITE and a regression).
__global__ __launch_bounds__(512, 2)
void fused_mem_kernel(const float* __restrict__ x, const float* __restrict__ wgt,
                      const _Float16* __restrict__ whi, const _Float16* __restrict__ wlo,
                      float* __restrict__ y_out, float* __restrict__ att_out) {
  // region: X stage f16[64][264] x2 = 67584 B -> B dbuf 2x65536 B -> yL f32[64][257]
  __shared__ __align__(16) float bufB[32768];       // 131072 B
  __shared__ int   lm[LCAP];
  __shared__ float le[LCAP];
  __shared__ float la[LCAP];
  __shared__ float Zred[256];
  __shared__ float invZ[TB];
  __shared__ float l1s[TB];
  __shared__ float dens[TB];
  __shared__ int   lcnt;
  _Float16* Xh = (_Float16*)bufB;
  _Float16* Xl = Xh + TB * XROW;
  float*    yL = bufB;
  char*     Bb = (char*)bufB;

  const int tid = threadIdx.x;
  const int wv  = tid >> 6;                 // 0..7
  const int l   = tid & 63;
  const int qw  = l >> 4;
  const int lr  = l & 15;
  const int mh  = wv & 3;                   // M quarter within 64-row tile
  const int tp  = wv >> 2;                  // token pair (32 tokens)
  const int t0  = blockIdx.x * TB;
  const int n   = t0 >> 10;
  const int hw0 = t0 & 1023;

  if (tid == 0) lcnt = 0;
  if (tid < TB) l1s[tid] = 0.f;

  // ---- phase 1: X tile (64 tokens x 256 c) -> LDS f16 hi/lo ----
  {
    const int h = tid & 63, cb = tid >> 6;
    const float* xp = x + ((size_t)n * Cc) * HW + hw0 + h;
    #pragma unroll
    for (int j = 0; j < 32; ++j) {
      int c = cb * 32 + j;
      float v = xp[(size_t)c * HW];          // 64 lanes consecutive: 256B chunks
      _Float16 hh = (_Float16)v;
      Xh[h * XROW + c] = hh;
      Xl[h * XROW + c] = (_Float16)((v - (float)hh) * SCL);
    }
  }
  __syncthreads();                                  // B1

  // A fragments: TWO 16-token sets per wave (tokens tp*32+0..15 and +16..31).
  // Per-set fragment contents/layout identical to the R2-verified mapping.
  f16x8 a0h[8], a0l[8], a1h[8], a1l[8];
  #pragma unroll
  for (int ks = 0; ks < 8; ++ks) {
    const int r0 = (tp * 32 + lr) * XROW + ks * 32 + qw * 8;
    const int r1 = (tp * 32 + 16 + lr) * XROW + ks * 32 + qw * 8;
    a0h[ks] = *(const f16x8*)&Xh[r0];
    a0l[ks] = *(const f16x8*)&Xl[r0];
    a1h[ks] = *(const f16x8*)&Xh[r1];
    a1l[ks] = *(const f16x8*)&Xl[r1];
  }
  __syncthreads();                                  // B1b: X region now free -> B dbuf

  // B staging (64 rows x 512B, hi then lo = 64KB/tile): linear LDS dest,
  // PRE-SWIZZLED global source (chunk ^= row&7); swizzled ds_read below matches.
  auto stage = [&](int b, int tile) {
    char* base = Bb + b * 65536;
    #pragma unroll
    for (int i = 0; i < 8; ++i) {
      const int bu = i * 512 + wv * 64;             // wave-uniform 16B-chunk base
      const int u2 = bu + l;                        // 0..4095
      const int r64 = (u2 >> 5) & 63;
      const int chunk = u2 & 31;
      int mrow = tile * 64 + r64; mrow = mrow < Mm ? mrow : (Mm - 1);  // tail clamp (rows unused)
      const char* src = (const char*)(u2 < 2048 ? whi : wlo)
                      + (size_t)mrow * 512 + ((chunk ^ (r64 & 7)) << 4);
      gl_lds16(src, base + u2 * 16);
    }
  };

  stage(0, 0);
  __syncthreads();                                  // B1c: tile0 landed (vmcnt drained)

  float zp0[4] = {0.f, 0.f, 0.f, 0.f};
  float zp1[4] = {0.f, 0.f, 0.f, 0.f};
  const int rrow = mh * 16 + lr;                    // W row within 64-row tile
  const int rsw  = rrow & 7;
  int cur = 0;
  for (int t = 0; t < NT; ++t) {
    if (t + 1 < NT) stage(cur ^ 1, t + 1);          // prefetch flies under compute

    // att background zeroing (block-exclusive slice; replaces the ~260us hipMemset)
    #pragma unroll
    for (int jj = 0; jj < 2; ++jj) {
      int m = t * 64 + jj * 32 + (tid >> 4);
      if (m < Mm) {
        f32x4 z4 = {0.f, 0.f, 0.f, 0.f};
        *(f32x4*)(att_out + ((size_t)(n * Mm + m)) * HW + hw0 + ((tid & 15) << 2)) = z4;
      }
    }

    if (t < NT - 1 || mh == 0) {                    // tail tile: 16 valid rows (mh==0 only)
      const char* bb = Bb + cur * 65536;
      f32x4 ahh0 = {0.f,0.f,0.f,0.f}, axl0 = {0.f,0.f,0.f,0.f}, alh0 = {0.f,0.f,0.f,0.f};
      f32x4 ahh1 = {0.f,0.f,0.f,0.f}, axl1 = {0.f,0.f,0.f,0.f}, alh1 = {0.f,0.f,0.f,0.f};
      #pragma unroll
      for (int kc = 0; kc < 2; ++kc) {              // B live range = 4 ks (32 regs)
        f16x8 bh[4], bl[4];
        #pragma unroll
        for (int k4 = 0; k4 < 4; ++k4) {
          const int ks = kc * 4 + k4;
          const int ch = rrow * 512 + (((ks * 4 + qw) ^ rsw) << 4);
          bh[k4] = *(const f16x8*)(bb + ch);
          bl[k4] = *(const f16x8*)(bb + 32768 + ch);
        }
        #pragma unroll
        for (int k4 = 0; k4 < 4; ++k4) {
          const int ks = kc * 4 + k4;
          ahh0 = __builtin_amdgcn_mfma_f32_16x16x32_f16(a0h[ks], bh[k4], ahh0, 0, 0, 0);
          axl0 = __builtin_amdgcn_mfma_f32_16x16x32_f16(a0h[ks], bl[k4], axl0, 0, 0, 0);
          alh0 = __builtin_amdgcn_mfma_f32_16x16x32_f16(a0l[ks], bh[k4], alh0, 0, 0, 0);
          ahh1 = __builtin_amdgcn_mfma_f32_16x16x32_f16(a1h[ks], bh[k4], ahh1, 0, 0, 0);
          axl1 = __builtin_amdgcn_mfma_f32_16x16x32_f16(a1h[ks], bl[k4], axl1, 0, 0, 0);
          alh1 = __builtin_amdgcn_mfma_f32_16x16x32_f16(a1l[ks], bh[k4], alh1, 0, 0, 0);
        }
      }
      const int mrow_ = t * 64 + rrow;
      #pragma unroll
      for (int r = 0; r < 4; ++r) {
        float s0 = fmaf(axl0[r] + alh0[r], ISCL, ahh0[r]);   // logit, bit-identical chains
        float e0 = __expf(s0);
        zp0[r] += e0;
        if (e0 > ECUT) {                                     // ~0.3% taken
          int slot = atomicAdd(&lcnt, 1);
          if (slot < LCAP) { lm[slot] = ((tp * 32 + qw * 4 + r) << 16) | mrow_; le[slot] = e0; }
        }
        float s1 = fmaf(axl1[r] + alh1[r], ISCL, ahh1[r]);
        float e1 = __expf(s1);
        zp1[r] += e1;
        if (e1 > ECUT) {
          int slot = atomicAdd(&lcnt, 1);
          if (slot < LCAP) { lm[slot] = ((tp * 32 + 16 + qw * 4 + r) << 16) | mrow_; le[slot] = e1; }
        }
      }
    }
    __syncthreads();                                // per-tile barrier (vmcnt drained)
    cur ^= 1;
  }

  #pragma unroll
  for (int o = 1; o < 16; o <<= 1)
    #pragma unroll
    for (int r = 0; r < 4; ++r) {
      zp0[r] += __shfl_xor(zp0[r], o);
      zp1[r] += __shfl_xor(zp1[r], o);
    }
  if (lr == 0) {
    #pragma unroll
    for (int r = 0; r < 4; ++r) {
      Zred[mh * 64 + tp * 32 + qw * 4 + r]      = zp0[r];
      Zred[mh * 64 + tp * 32 + 16 + qw * 4 + r] = zp1[r];
    }
  }
  __syncthreads();                                  // B2

  if (tid < TB)
    invZ[tid] = 1.f / (Zred[tid] + Zred[64 + tid] + Zred[128 + tid] + Zred[192 + tid]);
  __syncthreads();                                  // B3

  // ---- phase 4: candidate scan (exact fp32 recompute of borderline) + L1 ----
  const int ne = min(lcnt, LCAP);
  for (int e = tid; e < ne; e += 512) {
    const int tm = lm[e];
    const int t = tm >> 16, m = tm & 0xFFFF;
    float p = le[e] * invZ[t];
    float a = 0.f;
    if (p > PLO) {
      float pu = p;
      if (p < PHI) {
        // borderline (~few per block): exact fp32 dot from global x, W
        const float* xr = x + ((size_t)n * Cc) * HW + hw0 + t;
        const float* wr = wgt + (size_t)m * Cc;
        float s = 0.f;
        for (int c = 0; c < Cc; ++c) s = fmaf(xr[(size_t)c * HW], wr[c], s);
        pu = expf(s) * invZ[t];
      }
      float d = pu - LAMBDA;
      if (d > 0.f) {
        a = (d * pu) / (d + 1e-12f);
        atomicAdd(&l1s[t], a);
      }
    }
    la[e] = a;
  }
  __syncthreads();                                  // B4

  if (tid < TB) dens[tid] = fmaxf(l1s[tid], 1e-12f);
  for (int i = tid; i < TB * YROW; i += 512) yL[i] = 0.f;   // B dbuf dead; alias reuse
  __syncthreads();                                  // B5

  // ---- phase 6: sparse GEMM2 from survivor list (fp32 W) + att scatter ----
  // y accum layout PERMUTED: channel c lives at t*YROW + ((c&3)<<6 | c>>2) so the
  // atomics have 4B lane stride (2 lanes/bank = free).
  for (int e = wv; e < ne; e += 8) {                // wave-uniform entry -> no divergence
    float av = la[e];
    if (av > 0.f) {
      const int tm = lm[e];
      const int t = tm >> 16, m = tm & 0xFFFF;
      const float a = av / dens[t];
      float4 wf = *(const float4*)(wgt + (size_t)m * Cc + l * 4);   // c = 4l+i
      float* yr = yL + t * YROW + l;                // acc idx of c=4l+i is (i<<6)+l
      atomicAdd(yr + 0,   a * wf.x);
      atomicAdd(yr + 64,  a * wf.y);
      atomicAdd(yr + 128, a * wf.z);
      atomicAdd(yr + 192, a * wf.w);
      if (l == 0)
        att_out[((size_t)(n * Mm + m)) * HW + hw0 + t] = a;   // bg zeroed in-loop above
    }
  }
  __syncthreads();                                  // B6

  // ---- phase 7: y write (256B chunks: 64 consecutive hw per c); un-permute accum ----
  {
    const int h = tid & 63, cb = tid >> 6;
    float* yp = y_out + ((size_t)n * Cc) * HW + hw0 + h;
    #pragma unroll
    for (int j = 0; j < 32; ++j) {
      int c = cb * 32 + j;
      yp[(size_t)c * HW] = yL[h * YROW + (((c & 3) << 6) | (c >> 2))];
    }
  }
}

extern "C" void kernel_launch(void* const* d_in, const int* in_sizes, int n_in,
                              void* d_out, int out_size, void* d_ws, size_t ws_size,
                              hipStream_t stream) {
  const float* x = (const float*)d_in[0];
  const float* w = (const float*)d_in[1];
  float* y_out   = (float*)d_out;
  float* att_out = y_out + (size_t)Nn * Cc * HW;
  _Float16* whi = (_Float16*)d_ws;                  // 1.024 MB
  _Float16* wlo = whi + (size_t)Mm * Cc;            // 1.024 MB

  // no hipMemsetAsync: att background is zeroed in-kernel (block-exclusive slices);
  // the memset also evicted W from L2 before GEMM1.
  wcvt_kernel<<<(Mm * Cc + 255) / 256, 256, 0, stream>>>(w, whi, wlo);
  fused_mem_kernel<<<Tt / TB, 512, 0, stream>>>(x, w, whi, wlo, y_out, att_out);
}